// Round 3
// baseline (1696.868 us; speedup 1.0000x reference)
//
#include <hip/hip_runtime.h>
#include <hip/hip_bf16.h>

#define SEQ   4096
#define NFFT  8192
#define NCH   768
#define NB    16
#define KST   4104            // Kf row stride in float2 units (bins 0..4096 + pad)
#define LDSN  4368            // phys(4095)=4365

// padding spreads both stride-16 (->17) and stride-256 (->273) lane patterns
__device__ __forceinline__ int phys(int p) { return p + (p >> 4) + (p >> 8); }
__device__ __forceinline__ int br12(int k) { return (int)(__brev((unsigned)k) >> 20); }

__device__ __constant__ int BR4[16] = {0,8,4,12,2,10,6,14,1,9,5,13,3,11,7,15};

__device__ __forceinline__ float2 cmulf(float2 a, float2 b) {
  return make_float2(a.x*b.x - a.y*b.y, a.x*b.y + a.y*b.x);
}

// forward DIF butterfly: a' = a+b ; b' = (a-b)*w
__device__ __forceinline__ void bf_f(float2& a, float2& b, float wx, float wy) {
  float tx = a.x - b.x, ty = a.y - b.y;
  a.x += b.x; a.y += b.y;
  b.x = tx*wx - ty*wy;
  b.y = tx*wy + ty*wx;
}
// inverse DIT butterfly (conj twiddle internal, unnormalized)
__device__ __forceinline__ void bf_i(float2& a, float2& b, float wx, float wy) {
  float bx = b.x*wx + b.y*wy;
  float by = b.y*wx - b.x*wy;
  b.x = a.x - bx; b.y = a.y - by;
  a.x += bx; a.y += by;
}

#define C1X 0.9238795325112867f
#define C1Y (-0.3826834323650898f)
#define C2X 0.7071067811865476f
#define C2Y (-0.7071067811865476f)
#define C3X 0.3826834323650898f
#define C3Y (-0.9238795325112867f)

// spans 4,2,1 of the 16-pt DIF DFT (natural-in, bitrev4-slot-out overall)
__device__ __forceinline__ void dft16_f_tail(float2 v[16]) {
  bf_f(v[0], v[4],  1.f, 0.f);  bf_f(v[1], v[5],  C2X, C2Y);
  bf_f(v[2], v[6],  0.f, -1.f); bf_f(v[3], v[7],  -C2X, C2Y);
  bf_f(v[8], v[12], 1.f, 0.f);  bf_f(v[9], v[13], C2X, C2Y);
  bf_f(v[10],v[14], 0.f, -1.f); bf_f(v[11],v[15], -C2X, C2Y);
  bf_f(v[0], v[2], 1.f, 0.f);  bf_f(v[1], v[3], 0.f, -1.f);
  bf_f(v[4], v[6], 1.f, 0.f);  bf_f(v[5], v[7], 0.f, -1.f);
  bf_f(v[8], v[10],1.f, 0.f);  bf_f(v[9], v[11],0.f, -1.f);
  bf_f(v[12],v[14],1.f, 0.f);  bf_f(v[13],v[15],0.f, -1.f);
  bf_f(v[0], v[1], 1.f, 0.f);  bf_f(v[2], v[3], 1.f, 0.f);
  bf_f(v[4], v[5], 1.f, 0.f);  bf_f(v[6], v[7], 1.f, 0.f);
  bf_f(v[8], v[9], 1.f, 0.f);  bf_f(v[10],v[11],1.f, 0.f);
  bf_f(v[12],v[13],1.f, 0.f);  bf_f(v[14],v[15],1.f, 0.f);
}

__device__ __forceinline__ void dft16_f(float2 v[16]) {
  bf_f(v[0], v[8],  1.f, 0.f);
  bf_f(v[1], v[9],  C1X, C1Y);
  bf_f(v[2], v[10], C2X, C2Y);
  bf_f(v[3], v[11], C3X, C3Y);
  bf_f(v[4], v[12], 0.f, -1.f);
  bf_f(v[5], v[13], -C3X, C3Y);
  bf_f(v[6], v[14], -C2X, C2Y);
  bf_f(v[7], v[15], -C1X, C1Y);
  dft16_f_tail(v);
}

// inverse: bitrev4-slot-in, natural-out, scaled x16
__device__ __forceinline__ void dft16_i(float2 v[16]) {
  bf_i(v[0], v[1], 1.f, 0.f);  bf_i(v[2], v[3], 1.f, 0.f);
  bf_i(v[4], v[5], 1.f, 0.f);  bf_i(v[6], v[7], 1.f, 0.f);
  bf_i(v[8], v[9], 1.f, 0.f);  bf_i(v[10],v[11],1.f, 0.f);
  bf_i(v[12],v[13],1.f, 0.f);  bf_i(v[14],v[15],1.f, 0.f);
  bf_i(v[0], v[2], 1.f, 0.f);  bf_i(v[1], v[3], 0.f, -1.f);
  bf_i(v[4], v[6], 1.f, 0.f);  bf_i(v[5], v[7], 0.f, -1.f);
  bf_i(v[8], v[10],1.f, 0.f);  bf_i(v[9], v[11],0.f, -1.f);
  bf_i(v[12],v[14],1.f, 0.f);  bf_i(v[13],v[15],0.f, -1.f);
  bf_i(v[0], v[4],  1.f, 0.f);  bf_i(v[1], v[5],  C2X, C2Y);
  bf_i(v[2], v[6],  0.f, -1.f); bf_i(v[3], v[7],  -C2X, C2Y);
  bf_i(v[8], v[12], 1.f, 0.f);  bf_i(v[9], v[13], C2X, C2Y);
  bf_i(v[10],v[14], 0.f, -1.f); bf_i(v[11],v[15], -C2X, C2Y);
  bf_i(v[0], v[8],  1.f, 0.f);
  bf_i(v[1], v[9],  C1X, C1Y);
  bf_i(v[2], v[10], C2X, C2Y);
  bf_i(v[3], v[11], C3X, C3Y);
  bf_i(v[4], v[12], 0.f, -1.f);
  bf_i(v[5], v[13], -C3X, C3Y);
  bf_i(v[6], v[14], -C2X, C2Y);
  bf_i(v[7], v[15], -C1X, C1Y);
}

// log-depth twiddle powers (depth 4 vs 15-deep serial chain)
__device__ __forceinline__ void twiddle_apply(float2 v[16], float2 w1) {
  float2 w[16];
  w[1] = w1;
  w[2] = cmulf(w1, w1);
  w[4] = cmulf(w[2], w[2]);
  w[8] = cmulf(w[4], w[4]);
  w[3] = cmulf(w[1], w[2]);
  w[5] = cmulf(w[1], w[4]);
  w[6] = cmulf(w[2], w[4]);
  w[7] = cmulf(w[3], w[4]);
  w[9]  = cmulf(w[1], w[8]);
  w[10] = cmulf(w[2], w[8]);
  w[11] = cmulf(w[3], w[8]);
  w[12] = cmulf(w[4], w[8]);
  w[13] = cmulf(w[5], w[8]);
  w[14] = cmulf(w[6], w[8]);
  w[15] = cmulf(w[7], w[8]);
  #pragma unroll
  for (int r = 1; r < 16; ++r) v[BR4[r]] = cmulf(v[BR4[r]], w[r]);
}

__device__ __forceinline__ void twiddle_f(float2 v[16], int i, float invNP) {
  float sn, cs; __sincosf(-6.283185307179586f * (float)i * invNP, &sn, &cs);
  twiddle_apply(v, make_float2(cs, sn));
}
__device__ __forceinline__ void twiddle_i(float2 v[16], int i, float invNP) {
  float sn, cs; __sincosf(6.283185307179586f * (float)i * invNP, &sn, &cs);
  twiddle_apply(v, make_float2(cs, sn));
}

// first forward pass (NP=4096,G=256), input known zero for indices >= 2048;
// reads/writes only the calling thread's own slots {tid + m*256}
__device__ __forceinline__ void pass_f_first(float2* X, int tid) {
  float2 v[16];
  #pragma unroll
  for (int m = 0; m < 8; ++m) v[m] = X[phys(tid + m * 256)];
  v[8]  = v[0];
  v[9]  = cmulf(v[1], make_float2(C1X, C1Y));
  v[10] = cmulf(v[2], make_float2(C2X, C2Y));
  v[11] = cmulf(v[3], make_float2(C3X, C3Y));
  v[12] = make_float2(v[4].y, -v[4].x);
  v[13] = cmulf(v[5], make_float2(-C3X, C3Y));
  v[14] = cmulf(v[6], make_float2(-C2X, C2Y));
  v[15] = cmulf(v[7], make_float2(-C1X, C1Y));
  dft16_f_tail(v);
  if (tid) twiddle_f(v, tid, 1.0f / 4096.0f);
  #pragma unroll
  for (int s = 0; s < 16; ++s) X[phys(tid + s * 256)] = v[s];
}

template<int NP>
__device__ __forceinline__ void pass_f(float2* X, int tid) {
  constexpr int G = NP / 16;
  int i = tid & (G - 1);
  int base = (tid & ~(G - 1)) * 16 + i;
  float2 v[16];
  #pragma unroll
  for (int m = 0; m < 16; ++m) v[m] = X[phys(base + m * G)];
  dft16_f(v);
  if (G > 1 && i) twiddle_f(v, i, 1.0f / (float)NP);
  #pragma unroll
  for (int s = 0; s < 16; ++s) X[phys(base + s * G)] = v[s];
}

template<int NP>
__device__ __forceinline__ void pass_i(float2* X, int tid) {
  constexpr int G = NP / 16;
  int i = tid & (G - 1);
  int base = (tid & ~(G - 1)) * 16 + i;
  float2 v[16];
  #pragma unroll
  for (int s = 0; s < 16; ++s) v[s] = X[phys(base + s * G)];
  if (G > 1 && i) twiddle_i(v, i, 1.0f / (float)NP);
  dft16_i(v);
  #pragma unroll
  for (int m = 0; m < 16; ++m) X[phys(base + m * G)] = v[m];
}

__device__ __forceinline__ void fft_forward(float2* X, int tid) {
  pass_f_first(X, tid); __syncthreads();
  pass_f<256>(X, tid);  __syncthreads();
  pass_f<16>(X, tid);   __syncthreads();
}
// NOTE: no trailing barrier — pass_i<4096> touches only the calling thread's
// own slots {tid + m*256}, as do the subsequent store/fill/pass_f_first.
__device__ __forceinline__ void fft_inverse(float2* X, int tid) {
  pass_i<16>(X, tid);   __syncthreads();
  pass_i<256>(X, tid);  __syncthreads();
  pass_i<4096>(X, tid);
}

// rfft-halving unpack
__device__ __forceinline__ void unpack_pair(float2 Zk, float2 Zq, float c_, float s_,
                                            float2& Xk, float2& Xm) {
  float Ex = 0.5f*(Zk.x + Zq.x), Ey = 0.5f*(Zk.y - Zq.y);
  float Ox = 0.5f*(Zk.y + Zq.y), Oy = 0.5f*(Zq.x - Zk.x);
  Xk = make_float2(Ex + c_*Ox + s_*Oy,  Ey + c_*Oy - s_*Ox);
  Xm = make_float2(Ex - c_*Ox - s_*Oy, -Ey + c_*Oy - s_*Ox);
}

__device__ __forceinline__ float2 bf16pair_to_f2(unsigned int v) {
  return make_float2(__uint_as_float(v << 16), __uint_as_float(v & 0xFFFF0000u));
}
__device__ __forceinline__ unsigned int f2_to_bf16pair(float2 z) {
  unsigned int a = __float_as_uint(z.x), b = __float_as_uint(z.y);
  a = (a + 0x7FFFu + ((a >> 16) & 1u)) >> 16;
  b = (b + 0x7FFFu + ((b >> 16) & 1u)) & 0xFFFF0000u;
  return a | b;
}

// ---------------- kernel 1: implicit filter + FFT -> half spectrum ----------
__device__ __forceinline__ float mlp_eval(int n, const float* sw1, const float* sb1,
    const float* sw2, const float* sb2, const float* sfq, const float* sw3,
    float B3, float D) {
  float t = (float)n * (1.0f / 4095.0f);
  float fw = 1e-4f * 6.283185307179586f * (float)n / 4096.0f;
  float sfw, cfw; __sincosf(fw, &sfw, &cfw);
  float z0 = t, z1 = cfw, z2 = -sfw;
  float h1[16], h2[16];
  #pragma unroll
  for (int r = 0; r < 16; ++r)
    h1[r] = __sinf(sfq[r] * (z0 * sw1[3*r] + z1 * sw1[3*r+1] + z2 * sw1[3*r+2] + sb1[r]));
  #pragma unroll
  for (int r = 0; r < 16; ++r) {
    float acc = sb2[r];
    #pragma unroll
    for (int s = 0; s < 16; ++s) acc += h1[s] * sw2[16*r + s];
    h2[r] = __sinf(sfq[r] * acc);
  }
  float k = B3;
  #pragma unroll
  for (int r = 0; r < 16; ++r) k += h2[r] * sw3[r];
  return k * __expf(-t * D);
}

__global__ __launch_bounds__(256, 2) void filter_fft_kernel(
    const float* __restrict__ w1, const float* __restrict__ b1,
    const float* __restrict__ w2, const float* __restrict__ b2,
    const float* __restrict__ w3, const float* __restrict__ b3,
    const float* __restrict__ freq, const float* __restrict__ deltas,
    float2* __restrict__ Kf) {
  __shared__ float2 X[LDSN];
  __shared__ float sw1[48], sb1[16], sw2[256], sb2[16], sfq[16], sw3[16];
  int tid = threadIdx.x;
  int c = blockIdx.x;
  if (tid < 48) sw1[tid] = w1[tid];
  if (tid < 16) { sb1[tid] = b1[tid]; sb2[tid] = b2[tid]; sfq[tid] = freq[tid];
                  sw3[tid] = w3[(size_t)c * 16 + tid]; }
  sw2[tid] = w2[tid];
  float B3 = b3[c], D = deltas[c];
  __syncthreads();

  #pragma unroll
  for (int j = 0; j < 8; ++j) {
    int n2 = tid + 256 * j;
    float k0 = mlp_eval(2*n2,     sw1, sb1, sw2, sb2, sfq, sw3, B3, D);
    float k1 = mlp_eval(2*n2 + 1, sw1, sb1, sw2, sb2, sfq, sw3, B3, D);
    X[phys(n2)] = make_float2(k0, k1);
  }
  __syncthreads();

  fft_forward(X, tid);

  const float SC = 1.0f / 33554432.0f;   // 1/(8192*4096)
  float2* Kc = Kf + (size_t)c * KST;
  for (int k = tid; k <= 2048; k += 256) {
    int kq = (4096 - k) & 4095;
    float2 Zk = X[phys(br12(k))], Zq = X[phys(br12(kq))];
    float c_, s_; __sincosf((float)k * (3.14159265358979e0f / 4096.0f), &s_, &c_);
    float2 Xk, Xm;
    unpack_pair(Zk, Zq, c_, s_, Xk, Xm);
    Kc[k]        = make_float2(SC * Xk.x, SC * Xk.y);
    Kc[4096 - k] = make_float2(SC * Xm.x, SC * Xm.y);
  }
}

// ---------------- kernel 2: u[B,L,CH] -> bf16 ut[B,CH,L] --------------------
__global__ __launch_bounds__(256) void transpose_in(
    const float* __restrict__ u, __hip_bfloat16* __restrict__ ut) {
  __shared__ float tile[64][65];
  int i0 = blockIdx.x * 64, c0 = blockIdx.y * 64, b = blockIdx.z;
  int tr = threadIdx.x >> 6, tc = threadIdx.x & 63;
  const float* up = u + ((size_t)b * SEQ + i0) * NCH + c0;
  for (int r = tr; r < 64; r += 4) tile[r][tc] = up[(size_t)r * NCH + tc];
  __syncthreads();
  __hip_bfloat16* op = ut + ((size_t)b * NCH + c0) * SEQ + i0;
  for (int r = tr; r < 64; r += 4) op[(size_t)r * SEQ + tc] = __float2bfloat16(tile[tc][r]);
}

// ---------------- kernel 3: FFT conv, one block per channel, loop batches ---
__global__ __launch_bounds__(256, 2) void conv_kernel(
    __hip_bfloat16* __restrict__ ut, const float2* __restrict__ Kf) {
  __shared__ float2 X[LDSN];
  int tid = threadIdx.x;
  int c = blockIdx.x;
  const float2* Kc = Kf + (size_t)c * KST;

  unsigned int stage[8];
  {
    const unsigned int* row0 = (const unsigned int*)(ut + (size_t)c * SEQ);
    #pragma unroll
    for (int j = 0; j < 8; ++j) stage[j] = row0[tid + 256 * j];
  }

  for (int b = 0; b < NB; ++b) {
    unsigned int* row = (unsigned int*)(ut + ((size_t)b * NCH + c) * SEQ);

    // fill X from staged registers (own slots only)
    #pragma unroll
    for (int j = 0; j < 8; ++j) X[phys(tid + 256 * j)] = bf16pair_to_f2(stage[j]);

    // prefetch next batch's row; latency hides under the whole FFT
    if (b + 1 < NB) {
      const unsigned int* nrow = (const unsigned int*)(ut + ((size_t)(b + 1) * NCH + c) * SEQ);
      #pragma unroll
      for (int j = 0; j < 8; ++j) stage[j] = nrow[tid + 256 * j];
    }

    fft_forward(X, tid);

    // Hermitian unpack -> pointwise multiply -> repack for inverse
    for (int k = tid; k <= 2048; k += 256) {
      int kq = (4096 - k) & 4095;
      int p = phys(br12(k));
      int q = phys(br12(kq));
      float2 Zk = X[p], Zq = X[q];
      float c_, s_; __sincosf((float)k * (3.14159265358979e0f / 4096.0f), &s_, &c_);
      float2 Xk, Xm;
      unpack_pair(Zk, Zq, c_, s_, Xk, Xm);
      float2 Yk = cmulf(Xk, Kc[k]);
      float2 Ym = cmulf(Xm, Kc[4096 - k]);
      float Ax = 0.5f*(Yk.x + Ym.x), Ay = 0.5f*(Yk.y - Ym.y);
      float Bx = 0.5f*(Yk.x - Ym.x), By = 0.5f*(Yk.y + Ym.y);
      X[p] = make_float2(Ax - c_*By - s_*Bx,  Ay + c_*Bx - s_*By);
      X[q] = make_float2(Ax + c_*By + s_*Bx, -Ay + c_*Bx - s_*By);
    }
    __syncthreads();

    fft_inverse(X, tid);

    // store first 4096 samples (= 2048 packed complex) — exactly one row
    #pragma unroll
    for (int j = 0; j < 8; ++j) row[tid + 256 * j] = f2_to_bf16pair(X[phys(tid + 256 * j)]);
    // no barrier needed: next fill touches the same per-thread slots
  }
}

// ---------------- kernel 4: yt[B,CH,L] -> y[B,L,CH], fused + u*bias ---------
__global__ __launch_bounds__(256) void transpose_out(
    const __hip_bfloat16* __restrict__ yt, const float* __restrict__ u,
    const float* __restrict__ bias, float* __restrict__ y) {
  __shared__ float tile[64][65];
  int i0 = blockIdx.x * 64, c0 = blockIdx.y * 64, b = blockIdx.z;
  int tr = threadIdx.x >> 6, tc = threadIdx.x & 63;
  const __hip_bfloat16* yp = yt + ((size_t)b * NCH + c0) * SEQ + i0;
  for (int r = tr; r < 64; r += 4) tile[r][tc] = __bfloat162float(yp[(size_t)r * SEQ + tc]);
  __syncthreads();
  float bi = bias[c0 + tc];
  const float* up = u + ((size_t)b * SEQ + i0) * NCH + c0;
  float* op = y + ((size_t)b * SEQ + i0) * NCH + c0;
  for (int r = tr; r < 64; r += 4)
    op[(size_t)r * NCH + tc] = tile[tc][r] + up[(size_t)r * NCH + tc] * bi;
}

extern "C" void kernel_launch(void* const* d_in, const int* in_sizes, int n_in,
                              void* d_out, int out_size, void* d_ws, size_t ws_size,
                              hipStream_t stream) {
  const float* u      = (const float*)d_in[0];
  const float* w1     = (const float*)d_in[1];
  const float* b1     = (const float*)d_in[2];
  const float* w2     = (const float*)d_in[3];
  const float* b2     = (const float*)d_in[4];
  const float* w3     = (const float*)d_in[5];
  const float* b3     = (const float*)d_in[6];
  const float* freq   = (const float*)d_in[7];
  const float* deltas = (const float*)d_in[8];
  const float* bias   = (const float*)d_in[9];
  float* out = (float*)d_out;

  __hip_bfloat16* ut = (__hip_bfloat16*)d_ws;                         // 100,663,296 B
  float2* Kf = (float2*)((char*)d_ws + (size_t)NB * NCH * SEQ * 2);   // 25,214,976 B

  filter_fft_kernel<<<dim3(NCH), dim3(256), 0, stream>>>(w1, b1, w2, b2, w3, b3, freq, deltas, Kf);
  transpose_in<<<dim3(SEQ / 64, NCH / 64, NB), dim3(256), 0, stream>>>(u, ut);
  conv_kernel<<<dim3(NCH), dim3(256), 0, stream>>>(ut, Kf);
  transpose_out<<<dim3(SEQ / 64, NCH / 64, NB), dim3(256), 0, stream>>>(ut, u, bias, out);
}

// Round 5
// 529.359 us; speedup vs baseline: 3.2055x; 3.2055x over previous
//
#include <hip/hip_runtime.h>
#include <hip/hip_bf16.h>

#define SEQ   4096
#define NFFT  8192
#define NCH   768
#define NB    16
#define KST   4104            // Kf row stride in float2 units (bins 0..4096 + pad)
#define LDSN  4368            // phys(4095)=4365

// padding spreads both stride-16 (->17) and stride-256 (->273) lane patterns
__device__ __forceinline__ int phys(int p) { return p + (p >> 4) + (p >> 8); }
__device__ __forceinline__ int br12(int k) { return (int)(__brev((unsigned)k) >> 20); }

// constexpr (NOT __constant__ memory!) so BR4[r] folds at compile time after
// unrolling -> v[] stays statically indexed -> registers, not scratch.
constexpr int BR4[16] = {0,8,4,12,2,10,6,14,1,9,5,13,3,11,7,15};

__device__ __forceinline__ float2 cmulf(float2 a, float2 b) {
  return make_float2(a.x*b.x - a.y*b.y, a.x*b.y + a.y*b.x);
}

// forward DIF butterfly: a' = a+b ; b' = (a-b)*w
__device__ __forceinline__ void bf_f(float2& a, float2& b, float wx, float wy) {
  float tx = a.x - b.x, ty = a.y - b.y;
  a.x += b.x; a.y += b.y;
  b.x = tx*wx - ty*wy;
  b.y = tx*wy + ty*wx;
}
// inverse DIT butterfly (conj twiddle internal, unnormalized)
__device__ __forceinline__ void bf_i(float2& a, float2& b, float wx, float wy) {
  float bx = b.x*wx + b.y*wy;
  float by = b.y*wx - b.x*wy;
  b.x = a.x - bx; b.y = a.y - by;
  a.x += bx; a.y += by;
}

#define C1X 0.9238795325112867f
#define C1Y (-0.3826834323650898f)
#define C2X 0.7071067811865476f
#define C2Y (-0.7071067811865476f)
#define C3X 0.3826834323650898f
#define C3Y (-0.9238795325112867f)

// spans 4,2,1 of the 16-pt DIF DFT (natural-in, bitrev4-slot-out overall)
__device__ __forceinline__ void dft16_f_tail(float2 v[16]) {
  bf_f(v[0], v[4],  1.f, 0.f);  bf_f(v[1], v[5],  C2X, C2Y);
  bf_f(v[2], v[6],  0.f, -1.f); bf_f(v[3], v[7],  -C2X, C2Y);
  bf_f(v[8], v[12], 1.f, 0.f);  bf_f(v[9], v[13], C2X, C2Y);
  bf_f(v[10],v[14], 0.f, -1.f); bf_f(v[11],v[15], -C2X, C2Y);
  bf_f(v[0], v[2], 1.f, 0.f);  bf_f(v[1], v[3], 0.f, -1.f);
  bf_f(v[4], v[6], 1.f, 0.f);  bf_f(v[5], v[7], 0.f, -1.f);
  bf_f(v[8], v[10],1.f, 0.f);  bf_f(v[9], v[11],0.f, -1.f);
  bf_f(v[12],v[14],1.f, 0.f);  bf_f(v[13],v[15],0.f, -1.f);
  bf_f(v[0], v[1], 1.f, 0.f);  bf_f(v[2], v[3], 1.f, 0.f);
  bf_f(v[4], v[5], 1.f, 0.f);  bf_f(v[6], v[7], 1.f, 0.f);
  bf_f(v[8], v[9], 1.f, 0.f);  bf_f(v[10],v[11],1.f, 0.f);
  bf_f(v[12],v[13],1.f, 0.f);  bf_f(v[14],v[15],1.f, 0.f);
}

__device__ __forceinline__ void dft16_f(float2 v[16]) {
  bf_f(v[0], v[8],  1.f, 0.f);
  bf_f(v[1], v[9],  C1X, C1Y);
  bf_f(v[2], v[10], C2X, C2Y);
  bf_f(v[3], v[11], C3X, C3Y);
  bf_f(v[4], v[12], 0.f, -1.f);
  bf_f(v[5], v[13], -C3X, C3Y);
  bf_f(v[6], v[14], -C2X, C2Y);
  bf_f(v[7], v[15], -C1X, C1Y);
  dft16_f_tail(v);
}

// inverse: bitrev4-slot-in, natural-out, scaled x16
__device__ __forceinline__ void dft16_i(float2 v[16]) {
  bf_i(v[0], v[1], 1.f, 0.f);  bf_i(v[2], v[3], 1.f, 0.f);
  bf_i(v[4], v[5], 1.f, 0.f);  bf_i(v[6], v[7], 1.f, 0.f);
  bf_i(v[8], v[9], 1.f, 0.f);  bf_i(v[10],v[11],1.f, 0.f);
  bf_i(v[12],v[13],1.f, 0.f);  bf_i(v[14],v[15],1.f, 0.f);
  bf_i(v[0], v[2], 1.f, 0.f);  bf_i(v[1], v[3], 0.f, -1.f);
  bf_i(v[4], v[6], 1.f, 0.f);  bf_i(v[5], v[7], 0.f, -1.f);
  bf_i(v[8], v[10],1.f, 0.f);  bf_i(v[9], v[11],0.f, -1.f);
  bf_i(v[12],v[14],1.f, 0.f);  bf_i(v[13],v[15],0.f, -1.f);
  bf_i(v[0], v[4],  1.f, 0.f);  bf_i(v[1], v[5],  C2X, C2Y);
  bf_i(v[2], v[6],  0.f, -1.f); bf_i(v[3], v[7],  -C2X, C2Y);
  bf_i(v[8], v[12], 1.f, 0.f);  bf_i(v[9], v[13], C2X, C2Y);
  bf_i(v[10],v[14], 0.f, -1.f); bf_i(v[11],v[15], -C2X, C2Y);
  bf_i(v[0], v[8],  1.f, 0.f);
  bf_i(v[1], v[9],  C1X, C1Y);
  bf_i(v[2], v[10], C2X, C2Y);
  bf_i(v[3], v[11], C3X, C3Y);
  bf_i(v[4], v[12], 0.f, -1.f);
  bf_i(v[5], v[13], -C3X, C3Y);
  bf_i(v[6], v[14], -C2X, C2Y);
  bf_i(v[7], v[15], -C1X, C1Y);
}

// serial twiddle chain (2 live float2, 15-deep; latency hidden by TLP)
__device__ __forceinline__ void twiddle_apply(float2 v[16], float2 w1) {
  float2 wr = w1;
  #pragma unroll
  for (int r = 1; r < 16; ++r) { v[BR4[r]] = cmulf(v[BR4[r]], wr); wr = cmulf(wr, w1); }
}

__device__ __forceinline__ void twiddle_f(float2 v[16], int i, float invNP) {
  float sn, cs; __sincosf(-6.283185307179586f * (float)i * invNP, &sn, &cs);
  twiddle_apply(v, make_float2(cs, sn));
}
__device__ __forceinline__ void twiddle_i(float2 v[16], int i, float invNP) {
  float sn, cs; __sincosf(6.283185307179586f * (float)i * invNP, &sn, &cs);
  twiddle_apply(v, make_float2(cs, sn));
}

// first forward pass (NP=4096,G=256), input known zero for indices >= 2048;
// reads/writes only the calling thread's own slots {tid + m*256}
__device__ __forceinline__ void pass_f_first(float2* X, int tid) {
  float2 v[16];
  #pragma unroll
  for (int m = 0; m < 8; ++m) v[m] = X[phys(tid + m * 256)];
  v[8]  = v[0];
  v[9]  = cmulf(v[1], make_float2(C1X, C1Y));
  v[10] = cmulf(v[2], make_float2(C2X, C2Y));
  v[11] = cmulf(v[3], make_float2(C3X, C3Y));
  v[12] = make_float2(v[4].y, -v[4].x);
  v[13] = cmulf(v[5], make_float2(-C3X, C3Y));
  v[14] = cmulf(v[6], make_float2(-C2X, C2Y));
  v[15] = cmulf(v[7], make_float2(-C1X, C1Y));
  dft16_f_tail(v);
  if (tid) twiddle_f(v, tid, 1.0f / 4096.0f);
  #pragma unroll
  for (int s = 0; s < 16; ++s) X[phys(tid + s * 256)] = v[s];
}

template<int NP>
__device__ __forceinline__ void pass_f(float2* X, int tid) {
  constexpr int G = NP / 16;
  int i = tid & (G - 1);
  int base = (tid & ~(G - 1)) * 16 + i;
  float2 v[16];
  #pragma unroll
  for (int m = 0; m < 16; ++m) v[m] = X[phys(base + m * G)];
  dft16_f(v);
  if (G > 1 && i) twiddle_f(v, i, 1.0f / (float)NP);
  #pragma unroll
  for (int s = 0; s < 16; ++s) X[phys(base + s * G)] = v[s];
}

template<int NP>
__device__ __forceinline__ void pass_i(float2* X, int tid) {
  constexpr int G = NP / 16;
  int i = tid & (G - 1);
  int base = (tid & ~(G - 1)) * 16 + i;
  float2 v[16];
  #pragma unroll
  for (int s = 0; s < 16; ++s) v[s] = X[phys(base + s * G)];
  if (G > 1 && i) twiddle_i(v, i, 1.0f / (float)NP);
  dft16_i(v);
  #pragma unroll
  for (int m = 0; m < 16; ++m) X[phys(base + m * G)] = v[m];
}

// fill(own slots) -> pass_f_first(own slots): no leading barrier needed
__device__ __forceinline__ void fft_forward(float2* X, int tid) {
  pass_f_first(X, tid); __syncthreads();
  pass_f<256>(X, tid);  __syncthreads();
  pass_f<16>(X, tid);   __syncthreads();
}
// pass_i<4096> touches only own slots {tid+m*256}; store/fill after it too
__device__ __forceinline__ void fft_inverse(float2* X, int tid) {
  pass_i<16>(X, tid);   __syncthreads();
  pass_i<256>(X, tid);  __syncthreads();
  pass_i<4096>(X, tid);
}

// rfft-halving unpack
__device__ __forceinline__ void unpack_pair(float2 Zk, float2 Zq, float c_, float s_,
                                            float2& Xk, float2& Xm) {
  float Ex = 0.5f*(Zk.x + Zq.x), Ey = 0.5f*(Zk.y - Zq.y);
  float Ox = 0.5f*(Zk.y + Zq.y), Oy = 0.5f*(Zq.x - Zk.x);
  Xk = make_float2(Ex + c_*Ox + s_*Oy,  Ey + c_*Oy - s_*Ox);
  Xm = make_float2(Ex - c_*Ox - s_*Oy, -Ey + c_*Oy - s_*Ox);
}

__device__ __forceinline__ float2 bf16pair_to_f2(unsigned int v) {
  return make_float2(__uint_as_float(v << 16), __uint_as_float(v & 0xFFFF0000u));
}
__device__ __forceinline__ unsigned int f2_to_bf16pair(float2 z) {
  unsigned int a = __float_as_uint(z.x), b = __float_as_uint(z.y);
  a = (a + 0x7FFFu + ((a >> 16) & 1u)) >> 16;
  b = (b + 0x7FFFu + ((b >> 16) & 1u)) & 0xFFFF0000u;
  return a | b;
}

// ---------------- kernel 1: implicit filter + FFT -> half spectrum ----------
__device__ __forceinline__ float mlp_eval(int n, const float* sw1, const float* sb1,
    const float* sw2, const float* sb2, const float* sfq, const float* sw3,
    float B3, float D) {
  float t = (float)n * (1.0f / 4095.0f);
  float fw = 1e-4f * 6.283185307179586f * (float)n / 4096.0f;
  float sfw, cfw; __sincosf(fw, &sfw, &cfw);
  float z0 = t, z1 = cfw, z2 = -sfw;
  float h1[16], h2[16];
  #pragma unroll
  for (int r = 0; r < 16; ++r)
    h1[r] = __sinf(sfq[r] * (z0 * sw1[3*r] + z1 * sw1[3*r+1] + z2 * sw1[3*r+2] + sb1[r]));
  #pragma unroll
  for (int r = 0; r < 16; ++r) {
    float acc = sb2[r];
    #pragma unroll
    for (int s = 0; s < 16; ++s) acc += h1[s] * sw2[16*r + s];
    h2[r] = __sinf(sfq[r] * acc);
  }
  float k = B3;
  #pragma unroll
  for (int r = 0; r < 16; ++r) k += h2[r] * sw3[r];
  return k * __expf(-t * D);
}

__global__ __launch_bounds__(256) void filter_fft_kernel(
    const float* __restrict__ w1, const float* __restrict__ b1,
    const float* __restrict__ w2, const float* __restrict__ b2,
    const float* __restrict__ w3, const float* __restrict__ b3,
    const float* __restrict__ freq, const float* __restrict__ deltas,
    float2* __restrict__ Kf) {
  __shared__ float2 X[LDSN];
  __shared__ float sw1[48], sb1[16], sw2[256], sb2[16], sfq[16], sw3[16];
  int tid = threadIdx.x;
  int c = blockIdx.x;
  if (tid < 48) sw1[tid] = w1[tid];
  if (tid < 16) { sb1[tid] = b1[tid]; sb2[tid] = b2[tid]; sfq[tid] = freq[tid];
                  sw3[tid] = w3[(size_t)c * 16 + tid]; }
  sw2[tid] = w2[tid];
  float B3 = b3[c], D = deltas[c];
  __syncthreads();

  #pragma unroll
  for (int j = 0; j < 8; ++j) {
    int n2 = tid + 256 * j;
    float k0 = mlp_eval(2*n2,     sw1, sb1, sw2, sb2, sfq, sw3, B3, D);
    float k1 = mlp_eval(2*n2 + 1, sw1, sb1, sw2, sb2, sfq, sw3, B3, D);
    X[phys(n2)] = make_float2(k0, k1);
  }

  fft_forward(X, tid);

  const float SC = 1.0f / 33554432.0f;   // 1/(8192*4096)
  float2* Kc = Kf + (size_t)c * KST;
  for (int k = tid; k <= 2048; k += 256) {
    int kq = (4096 - k) & 4095;
    float2 Zk = X[phys(br12(k))], Zq = X[phys(br12(kq))];
    float c_, s_; __sincosf((float)k * (3.14159265358979e0f / 4096.0f), &s_, &c_);
    float2 Xk, Xm;
    unpack_pair(Zk, Zq, c_, s_, Xk, Xm);
    Kc[k]        = make_float2(SC * Xk.x, SC * Xk.y);
    Kc[4096 - k] = make_float2(SC * Xm.x, SC * Xm.y);
  }
}

// ---------------- kernel 2: u[B,L,CH] -> bf16 ut[B,CH,L] --------------------
__global__ __launch_bounds__(256) void transpose_in(
    const float* __restrict__ u, __hip_bfloat16* __restrict__ ut) {
  __shared__ float tile[64][65];
  int i0 = blockIdx.x * 64, c0 = blockIdx.y * 64, b = blockIdx.z;
  int tr = threadIdx.x >> 6, tc = threadIdx.x & 63;
  const float* up = u + ((size_t)b * SEQ + i0) * NCH + c0;
  for (int r = tr; r < 64; r += 4) tile[r][tc] = up[(size_t)r * NCH + tc];
  __syncthreads();
  __hip_bfloat16* op = ut + ((size_t)b * NCH + c0) * SEQ + i0;
  for (int r = tr; r < 64; r += 4) op[(size_t)r * SEQ + tc] = __float2bfloat16(tile[tc][r]);
}

// ---------------- kernel 3: FFT conv per (channel, batch), in place ---------
// chunked XCD swizzle: each XCD owns 96 contiguous channels (3.1 MB of Kf,
// L2-resident) x all 16 batches.
__global__ __launch_bounds__(256) void conv_kernel(
    __hip_bfloat16* __restrict__ ut, const float2* __restrict__ Kf) {
  __shared__ float2 X[LDSN];
  int tid = threadIdx.x;
  int wg  = blockIdx.x;
  int id  = (wg & 7) * (NCH * NB / 8) + (wg >> 3);   // bijective: 12288 % 8 == 0
  int c   = id >> 4;
  int b   = id & 15;
  unsigned int* row = (unsigned int*)(ut + ((size_t)b * NCH + c) * SEQ);
  const float2* Kc = Kf + (size_t)c * KST;

  // load 4096 bf16 as 2048 packed complex into lower half (own slots only)
  #pragma unroll
  for (int j = 0; j < 8; ++j) {
    int n2 = tid + 256 * j;
    X[phys(n2)] = bf16pair_to_f2(row[n2]);
  }

  fft_forward(X, tid);

  // Hermitian unpack -> pointwise multiply -> repack for inverse
  for (int k = tid; k <= 2048; k += 256) {
    int kq = (4096 - k) & 4095;
    int p = phys(br12(k));
    int q = phys(br12(kq));
    float2 Zk = X[p], Zq = X[q];
    float c_, s_; __sincosf((float)k * (3.14159265358979e0f / 4096.0f), &s_, &c_);
    float2 Xk, Xm;
    unpack_pair(Zk, Zq, c_, s_, Xk, Xm);
    float2 Yk = cmulf(Xk, Kc[k]);
    float2 Ym = cmulf(Xm, Kc[4096 - k]);
    float Ax = 0.5f*(Yk.x + Ym.x), Ay = 0.5f*(Yk.y - Ym.y);
    float Bx = 0.5f*(Yk.x - Ym.x), By = 0.5f*(Yk.y + Ym.y);
    X[p] = make_float2(Ax - c_*By - s_*Bx,  Ay + c_*Bx - s_*By);
    X[q] = make_float2(Ax + c_*By + s_*Bx, -Ay + c_*Bx - s_*By);
  }
  __syncthreads();

  fft_inverse(X, tid);

  // store first 4096 samples (= 2048 packed complex) — exactly one row
  #pragma unroll
  for (int j = 0; j < 8; ++j) {
    int n2 = tid + 256 * j;
    row[n2] = f2_to_bf16pair(X[phys(n2)]);
  }
}

// ---------------- kernel 4: yt[B,CH,L] -> y[B,L,CH], fused + u*bias ---------
__global__ __launch_bounds__(256) void transpose_out(
    const __hip_bfloat16* __restrict__ yt, const float* __restrict__ u,
    const float* __restrict__ bias, float* __restrict__ y) {
  __shared__ float tile[64][65];
  int i0 = blockIdx.x * 64, c0 = blockIdx.y * 64, b = blockIdx.z;
  int tr = threadIdx.x >> 6, tc = threadIdx.x & 63;
  const __hip_bfloat16* yp = yt + ((size_t)b * NCH + c0) * SEQ + i0;
  for (int r = tr; r < 64; r += 4) tile[r][tc] = __bfloat162float(yp[(size_t)r * SEQ + tc]);
  __syncthreads();
  float bi = bias[c0 + tc];
  const float* up = u + ((size_t)b * SEQ + i0) * NCH + c0;
  float* op = y + ((size_t)b * SEQ + i0) * NCH + c0;
  for (int r = tr; r < 64; r += 4)
    op[(size_t)r * NCH + tc] = tile[tc][r] + up[(size_t)r * NCH + tc] * bi;
}

extern "C" void kernel_launch(void* const* d_in, const int* in_sizes, int n_in,
                              void* d_out, int out_size, void* d_ws, size_t ws_size,
                              hipStream_t stream) {
  const float* u      = (const float*)d_in[0];
  const float* w1     = (const float*)d_in[1];
  const float* b1     = (const float*)d_in[2];
  const float* w2     = (const float*)d_in[3];
  const float* b2     = (const float*)d_in[4];
  const float* w3     = (const float*)d_in[5];
  const float* b3     = (const float*)d_in[6];
  const float* freq   = (const float*)d_in[7];
  const float* deltas = (const float*)d_in[8];
  const float* bias   = (const float*)d_in[9];
  float* out = (float*)d_out;

  __hip_bfloat16* ut = (__hip_bfloat16*)d_ws;                         // 100,663,296 B
  float2* Kf = (float2*)((char*)d_ws + (size_t)NB * NCH * SEQ * 2);   // 25,214,976 B

  filter_fft_kernel<<<dim3(NCH), dim3(256), 0, stream>>>(w1, b1, w2, b2, w3, b3, freq, deltas, Kf);
  transpose_in<<<dim3(SEQ / 64, NCH / 64, NB), dim3(256), 0, stream>>>(u, ut);
  conv_kernel<<<dim3(NCH * NB), dim3(256), 0, stream>>>(ut, Kf);
  transpose_out<<<dim3(SEQ / 64, NCH / 64, NB), dim3(256), 0, stream>>>(ut, u, bias, out);
}

// Round 6
// 485.872 us; speedup vs baseline: 3.4924x; 1.0895x over previous
//
#include <hip/hip_runtime.h>
#include <hip/hip_bf16.h>

#define SEQ   4096
#define NFFT  8192
#define NCH   768
#define NB    16
#define KST   4104            // Kf row stride in cf units (bins 0..4096 + pad)
#define LDSN  4368            // phys(4095)=4365

// packed complex float: clang lowers +,-,* to v_pk_{add,mul,fma}_f32 on gfx950
typedef float cf __attribute__((ext_vector_type(2)));

// padding spreads both stride-16 (->17) and stride-256 (->273) lane patterns
__device__ __forceinline__ int phys(int p) { return p + (p >> 4) + (p >> 8); }
__device__ __forceinline__ int br12(int k) { return (int)(__brev((unsigned)k) >> 20); }

// constexpr (NOT __constant__ memory!) so BR4[r] folds at compile time after
// unrolling -> v[] stays statically indexed -> registers, not scratch.
constexpr int BR4[16] = {0,8,4,12,2,10,6,14,1,9,5,13,3,11,7,15};

// a*w given iw = i*w:  r = a.xx*w + a.yy*iw  -> pk_mul + pk_fma (op_sel folds)
__device__ __forceinline__ cf cmul_wi(cf a, cf w, cf iw) {
  cf axx = __builtin_shufflevector(a, a, 0, 0);
  cf ayy = __builtin_shufflevector(a, a, 1, 1);
  return axx * w + ayy * iw;
}
__device__ __forceinline__ cf icmul(cf a) { return cf{-a.y, a.x}; }  // i*a
__device__ __forceinline__ cf cmul(cf a, cf b) { return cmul_wi(a, b, icmul(b)); }

// multiply by compile-time constant (WX,WY): iw folded at compile time
#define CMULC(a, WX, WY) cmul_wi(a, cf{(WX),(WY)}, cf{-(WY),(WX)})

#define C1X 0.9238795325112867f
#define C1Y (-0.3826834323650898f)
#define C2X 0.7071067811865476f
#define C2Y (-0.7071067811865476f)
#define C3X 0.3826834323650898f
#define C3Y (-0.9238795325112867f)

// forward DIF butterfly: a' = a+b ; b' = (a-b)*w
#define BF_F(a, b, WX, WY) { cf t_ = a - b; a = a + b; b = CMULC(t_, WX, WY); }
#define BF_F1(a, b)        { cf t_ = a - b; a = a + b; b = t_; }
#define BF_FJ(a, b)        { cf t_ = a - b; a = a + b; b = cf{t_.y, -t_.x}; }  // *( -i )
// inverse DIT butterfly: t = b*conj(w); b' = a-t ; a' = a+t
#define BF_I(a, b, WX, WY) { cf t_ = cmul_wi(b, cf{(WX),-(WY)}, cf{(WY),(WX)}); b = a - t_; a = a + t_; }
#define BF_I1(a, b)        { cf t_ = b; b = a - t_; a = a + t_; }
#define BF_IJ(a, b)        { cf t_ = cf{-b.y, b.x}; b = a - t_; a = a + t_; }   // *conj(-i)=*i

// spans 4,2,1 of the 16-pt DIF DFT (natural-in, bitrev4-slot-out overall)
__device__ __forceinline__ void dft16_f_tail(cf v[16]) {
  BF_F1(v[0], v[4]);            BF_F(v[1], v[5],  C2X, C2Y);
  BF_FJ(v[2], v[6]);            BF_F(v[3], v[7], -C2X, C2Y);
  BF_F1(v[8], v[12]);           BF_F(v[9], v[13], C2X, C2Y);
  BF_FJ(v[10], v[14]);          BF_F(v[11], v[15], -C2X, C2Y);
  BF_F1(v[0], v[2]);  BF_FJ(v[1], v[3]);
  BF_F1(v[4], v[6]);  BF_FJ(v[5], v[7]);
  BF_F1(v[8], v[10]); BF_FJ(v[9], v[11]);
  BF_F1(v[12], v[14]); BF_FJ(v[13], v[15]);
  BF_F1(v[0], v[1]);  BF_F1(v[2], v[3]);
  BF_F1(v[4], v[5]);  BF_F1(v[6], v[7]);
  BF_F1(v[8], v[9]);  BF_F1(v[10], v[11]);
  BF_F1(v[12], v[13]); BF_F1(v[14], v[15]);
}

__device__ __forceinline__ void dft16_f(cf v[16]) {
  BF_F1(v[0], v[8]);
  BF_F(v[1], v[9],  C1X, C1Y);
  BF_F(v[2], v[10], C2X, C2Y);
  BF_F(v[3], v[11], C3X, C3Y);
  BF_FJ(v[4], v[12]);
  BF_F(v[5], v[13], -C3X, C3Y);
  BF_F(v[6], v[14], -C2X, C2Y);
  BF_F(v[7], v[15], -C1X, C1Y);
  dft16_f_tail(v);
}

// inverse: bitrev4-slot-in, natural-out, scaled x16
__device__ __forceinline__ void dft16_i(cf v[16]) {
  BF_I1(v[0], v[1]);  BF_I1(v[2], v[3]);
  BF_I1(v[4], v[5]);  BF_I1(v[6], v[7]);
  BF_I1(v[8], v[9]);  BF_I1(v[10], v[11]);
  BF_I1(v[12], v[13]); BF_I1(v[14], v[15]);
  BF_I1(v[0], v[2]);  BF_IJ(v[1], v[3]);
  BF_I1(v[4], v[6]);  BF_IJ(v[5], v[7]);
  BF_I1(v[8], v[10]); BF_IJ(v[9], v[11]);
  BF_I1(v[12], v[14]); BF_IJ(v[13], v[15]);
  BF_I1(v[0], v[4]);            BF_I(v[1], v[5],  C2X, C2Y);
  BF_IJ(v[2], v[6]);            BF_I(v[3], v[7], -C2X, C2Y);
  BF_I1(v[8], v[12]);           BF_I(v[9], v[13], C2X, C2Y);
  BF_IJ(v[10], v[14]);          BF_I(v[11], v[15], -C2X, C2Y);
  BF_I1(v[0], v[8]);
  BF_I(v[1], v[9],  C1X, C1Y);
  BF_I(v[2], v[10], C2X, C2Y);
  BF_I(v[3], v[11], C3X, C3Y);
  BF_IJ(v[4], v[12]);
  BF_I(v[5], v[13], -C3X, C3Y);
  BF_I(v[6], v[14], -C2X, C2Y);
  BF_I(v[7], v[15], -C1X, C1Y);
}

// serial twiddle chain with precomputed iw companions
__device__ __forceinline__ void twiddle_apply(cf v[16], cf w1) {
  cf iw1 = icmul(w1);
  cf wr = w1, iwr = iw1;
  #pragma unroll
  for (int r = 1; r < 16; ++r) {
    v[BR4[r]] = cmul_wi(v[BR4[r]], wr, iwr);
    if (r < 15) { wr = cmul_wi(wr, w1, iw1); iwr = icmul(wr); }
  }
}

__device__ __forceinline__ void twiddle_f(cf v[16], int i, float invNP) {
  float sn, cs; __sincosf(-6.283185307179586f * (float)i * invNP, &sn, &cs);
  twiddle_apply(v, cf{cs, sn});
}
__device__ __forceinline__ void twiddle_i(cf v[16], int i, float invNP) {
  float sn, cs; __sincosf(6.283185307179586f * (float)i * invNP, &sn, &cs);
  twiddle_apply(v, cf{cs, sn});
}

// first forward pass (NP=4096,G=256), input known zero for indices >= 2048;
// reads/writes only the calling thread's own slots {tid + m*256}
__device__ __forceinline__ void pass_f_first(cf* X, int tid) {
  cf v[16];
  #pragma unroll
  for (int m = 0; m < 8; ++m) v[m] = X[phys(tid + m * 256)];
  v[8]  = v[0];
  v[9]  = CMULC(v[1],  C1X, C1Y);
  v[10] = CMULC(v[2],  C2X, C2Y);
  v[11] = CMULC(v[3],  C3X, C3Y);
  v[12] = cf{v[4].y, -v[4].x};
  v[13] = CMULC(v[5], -C3X, C3Y);
  v[14] = CMULC(v[6], -C2X, C2Y);
  v[15] = CMULC(v[7], -C1X, C1Y);
  dft16_f_tail(v);
  if (tid) twiddle_f(v, tid, 1.0f / 4096.0f);
  #pragma unroll
  for (int s = 0; s < 16; ++s) X[phys(tid + s * 256)] = v[s];
}

template<int NP>
__device__ __forceinline__ void pass_f(cf* X, int tid) {
  constexpr int G = NP / 16;
  int i = tid & (G - 1);
  int base = (tid & ~(G - 1)) * 16 + i;
  cf v[16];
  #pragma unroll
  for (int m = 0; m < 16; ++m) v[m] = X[phys(base + m * G)];
  dft16_f(v);
  if (G > 1 && i) twiddle_f(v, i, 1.0f / (float)NP);
  #pragma unroll
  for (int s = 0; s < 16; ++s) X[phys(base + s * G)] = v[s];
}

template<int NP>
__device__ __forceinline__ void pass_i(cf* X, int tid) {
  constexpr int G = NP / 16;
  int i = tid & (G - 1);
  int base = (tid & ~(G - 1)) * 16 + i;
  cf v[16];
  #pragma unroll
  for (int s = 0; s < 16; ++s) v[s] = X[phys(base + s * G)];
  if (G > 1 && i) twiddle_i(v, i, 1.0f / (float)NP);
  dft16_i(v);
  #pragma unroll
  for (int m = 0; m < 16; ++m) X[phys(base + m * G)] = v[m];
}

// fill(own slots) -> pass_f_first(own slots): no leading barrier needed
__device__ __forceinline__ void fft_forward(cf* X, int tid) {
  pass_f_first(X, tid); __syncthreads();
  pass_f<256>(X, tid);  __syncthreads();
  pass_f<16>(X, tid);   __syncthreads();
}
// pass_i<4096> touches only own slots {tid+m*256}; store/fill after it too
__device__ __forceinline__ void fft_inverse(cf* X, int tid) {
  pass_i<16>(X, tid);   __syncthreads();
  pass_i<256>(X, tid);  __syncthreads();
  pass_i<4096>(X, tid);
}

// rfft-halving unpack
__device__ __forceinline__ void unpack_pair(cf Zk, cf Zq, float c_, float s_,
                                            cf& Xk, cf& Xm) {
  float Ex = 0.5f*(Zk.x + Zq.x), Ey = 0.5f*(Zk.y - Zq.y);
  float Ox = 0.5f*(Zk.y + Zq.y), Oy = 0.5f*(Zq.x - Zk.x);
  Xk = cf{Ex + c_*Ox + s_*Oy,  Ey + c_*Oy - s_*Ox};
  Xm = cf{Ex - c_*Ox - s_*Oy, -Ey + c_*Oy - s_*Ox};
}

__device__ __forceinline__ cf bf16pair_to_cf(unsigned int v) {
  return cf{__uint_as_float(v << 16), __uint_as_float(v & 0xFFFF0000u)};
}
__device__ __forceinline__ unsigned int cf_to_bf16pair(cf z) {
  unsigned int a = __float_as_uint(z.x), b = __float_as_uint(z.y);
  a = (a + 0x7FFFu + ((a >> 16) & 1u)) >> 16;
  b = (b + 0x7FFFu + ((b >> 16) & 1u)) & 0xFFFF0000u;
  return a | b;
}

// ---------------- kernel 1: implicit filter + FFT -> half spectrum ----------
__device__ __forceinline__ float mlp_eval(int n, const float* sw1, const float* sb1,
    const float* sw2, const float* sb2, const float* sfq, const float* sw3,
    float B3, float D) {
  float t = (float)n * (1.0f / 4095.0f);
  float fw = 1e-4f * 6.283185307179586f * (float)n / 4096.0f;
  float sfw, cfw; __sincosf(fw, &sfw, &cfw);
  float z0 = t, z1 = cfw, z2 = -sfw;
  float h1[16], h2[16];
  #pragma unroll
  for (int r = 0; r < 16; ++r)
    h1[r] = __sinf(sfq[r] * (z0 * sw1[3*r] + z1 * sw1[3*r+1] + z2 * sw1[3*r+2] + sb1[r]));
  #pragma unroll
  for (int r = 0; r < 16; ++r) {
    float acc = sb2[r];
    #pragma unroll
    for (int s = 0; s < 16; ++s) acc += h1[s] * sw2[16*r + s];
    h2[r] = __sinf(sfq[r] * acc);
  }
  float k = B3;
  #pragma unroll
  for (int r = 0; r < 16; ++r) k += h2[r] * sw3[r];
  return k * __expf(-t * D);
}

__global__ __launch_bounds__(256) void filter_fft_kernel(
    const float* __restrict__ w1, const float* __restrict__ b1,
    const float* __restrict__ w2, const float* __restrict__ b2,
    const float* __restrict__ w3, const float* __restrict__ b3,
    const float* __restrict__ freq, const float* __restrict__ deltas,
    cf* __restrict__ Kf) {
  __shared__ cf X[LDSN];
  __shared__ float sw1[48], sb1[16], sw2[256], sb2[16], sfq[16], sw3[16];
  int tid = threadIdx.x;
  int c = blockIdx.x;
  if (tid < 48) sw1[tid] = w1[tid];
  if (tid < 16) { sb1[tid] = b1[tid]; sb2[tid] = b2[tid]; sfq[tid] = freq[tid];
                  sw3[tid] = w3[(size_t)c * 16 + tid]; }
  sw2[tid] = w2[tid];
  float B3 = b3[c], D = deltas[c];
  __syncthreads();

  #pragma unroll
  for (int j = 0; j < 8; ++j) {
    int n2 = tid + 256 * j;
    float k0 = mlp_eval(2*n2,     sw1, sb1, sw2, sb2, sfq, sw3, B3, D);
    float k1 = mlp_eval(2*n2 + 1, sw1, sb1, sw2, sb2, sfq, sw3, B3, D);
    X[phys(n2)] = cf{k0, k1};
  }

  fft_forward(X, tid);

  const float SC = 1.0f / 33554432.0f;   // 1/(8192*4096)
  cf* Kc = Kf + (size_t)c * KST;
  for (int k = tid; k <= 2048; k += 256) {
    int kq = (4096 - k) & 4095;
    cf Zk = X[phys(br12(k))], Zq = X[phys(br12(kq))];
    float c_, s_; __sincosf((float)k * (3.14159265358979e0f / 4096.0f), &s_, &c_);
    cf Xk, Xm;
    unpack_pair(Zk, Zq, c_, s_, Xk, Xm);
    Kc[k]        = SC * Xk;
    Kc[4096 - k] = SC * Xm;
  }
}

// ---------------- kernel 2: u[B,L,CH] -> bf16 ut[B,CH,L] --------------------
__global__ __launch_bounds__(256) void transpose_in(
    const float* __restrict__ u, __hip_bfloat16* __restrict__ ut) {
  __shared__ float tile[64][65];
  int i0 = blockIdx.x * 64, c0 = blockIdx.y * 64, b = blockIdx.z;
  int tr = threadIdx.x >> 6, tc = threadIdx.x & 63;
  const float* up = u + ((size_t)b * SEQ + i0) * NCH + c0;
  for (int r = tr; r < 64; r += 4) tile[r][tc] = up[(size_t)r * NCH + tc];
  __syncthreads();
  __hip_bfloat16* op = ut + ((size_t)b * NCH + c0) * SEQ + i0;
  for (int r = tr; r < 64; r += 4) op[(size_t)r * SEQ + tc] = __float2bfloat16(tile[tc][r]);
}

// ---------------- kernel 3: FFT conv per (channel, batch), in place ---------
// chunked XCD swizzle: each XCD owns 96 contiguous channels (3.1 MB of Kf,
// L2-resident) x all 16 batches.
__global__ __launch_bounds__(256) void conv_kernel(
    __hip_bfloat16* __restrict__ ut, const cf* __restrict__ Kf) {
  __shared__ cf X[LDSN];
  int tid = threadIdx.x;
  int wg  = blockIdx.x;
  int id  = (wg & 7) * (NCH * NB / 8) + (wg >> 3);   // bijective: 12288 % 8 == 0
  int c   = id >> 4;
  int b   = id & 15;
  unsigned int* row = (unsigned int*)(ut + ((size_t)b * NCH + c) * SEQ);
  const cf* Kc = Kf + (size_t)c * KST;

  // load 4096 bf16 as 2048 packed complex into lower half (own slots only)
  #pragma unroll
  for (int j = 0; j < 8; ++j) {
    int n2 = tid + 256 * j;
    X[phys(n2)] = bf16pair_to_cf(row[n2]);
  }

  fft_forward(X, tid);

  // Hermitian unpack -> pointwise multiply -> repack for inverse
  for (int k = tid; k <= 2048; k += 256) {
    int kq = (4096 - k) & 4095;
    int p = phys(br12(k));
    int q = phys(br12(kq));
    cf Zk = X[p], Zq = X[q];
    float c_, s_; __sincosf((float)k * (3.14159265358979e0f / 4096.0f), &s_, &c_);
    cf Xk, Xm;
    unpack_pair(Zk, Zq, c_, s_, Xk, Xm);
    cf Yk = cmul(Xk, Kc[k]);
    cf Ym = cmul(Xm, Kc[4096 - k]);
    float Ax = 0.5f*(Yk.x + Ym.x), Ay = 0.5f*(Yk.y - Ym.y);
    float Bx = 0.5f*(Yk.x - Ym.x), By = 0.5f*(Yk.y + Ym.y);
    X[p] = cf{Ax - c_*By - s_*Bx,  Ay + c_*Bx - s_*By};
    X[q] = cf{Ax + c_*By + s_*Bx, -Ay + c_*Bx - s_*By};
  }
  __syncthreads();

  fft_inverse(X, tid);

  // store first 4096 samples (= 2048 packed complex) — exactly one row
  #pragma unroll
  for (int j = 0; j < 8; ++j) {
    int n2 = tid + 256 * j;
    row[n2] = cf_to_bf16pair(X[phys(n2)]);
  }
}

// ---------------- kernel 4: yt[B,CH,L] -> y[B,L,CH], fused + u*bias ---------
__global__ __launch_bounds__(256) void transpose_out(
    const __hip_bfloat16* __restrict__ yt, const float* __restrict__ u,
    const float* __restrict__ bias, float* __restrict__ y) {
  __shared__ float tile[64][65];
  int i0 = blockIdx.x * 64, c0 = blockIdx.y * 64, b = blockIdx.z;
  int tr = threadIdx.x >> 6, tc = threadIdx.x & 63;
  const __hip_bfloat16* yp = yt + ((size_t)b * NCH + c0) * SEQ + i0;
  for (int r = tr; r < 64; r += 4) tile[r][tc] = __bfloat162float(yp[(size_t)r * SEQ + tc]);
  __syncthreads();
  float bi = bias[c0 + tc];
  const float* up = u + ((size_t)b * SEQ + i0) * NCH + c0;
  float* op = y + ((size_t)b * SEQ + i0) * NCH + c0;
  for (int r = tr; r < 64; r += 4)
    op[(size_t)r * NCH + tc] = tile[tc][r] + up[(size_t)r * NCH + tc] * bi;
}

extern "C" void kernel_launch(void* const* d_in, const int* in_sizes, int n_in,
                              void* d_out, int out_size, void* d_ws, size_t ws_size,
                              hipStream_t stream) {
  const float* u      = (const float*)d_in[0];
  const float* w1     = (const float*)d_in[1];
  const float* b1     = (const float*)d_in[2];
  const float* w2     = (const float*)d_in[3];
  const float* b2     = (const float*)d_in[4];
  const float* w3     = (const float*)d_in[5];
  const float* b3     = (const float*)d_in[6];
  const float* freq   = (const float*)d_in[7];
  const float* deltas = (const float*)d_in[8];
  const float* bias   = (const float*)d_in[9];
  float* out = (float*)d_out;

  __hip_bfloat16* ut = (__hip_bfloat16*)d_ws;                     // 100,663,296 B
  cf* Kf = (cf*)((char*)d_ws + (size_t)NB * NCH * SEQ * 2);       // 25,214,976 B

  filter_fft_kernel<<<dim3(NCH), dim3(256), 0, stream>>>(w1, b1, w2, b2, w3, b3, freq, deltas, Kf);
  transpose_in<<<dim3(SEQ / 64, NCH / 64, NB), dim3(256), 0, stream>>>(u, ut);
  conv_kernel<<<dim3(NCH * NB), dim3(256), 0, stream>>>(ut, Kf);
  transpose_out<<<dim3(SEQ / 64, NCH / 64, NB), dim3(256), 0, stream>>>(ut, u, bias, out);
}